// Round 7
// baseline (612.862 us; speedup 1.0000x reference)
//
#include <hip/hip_runtime.h>
#include <stddef.h>

static constexpr int Nn    = 100000;   // nodes
static constexpr int Ee    = 1600000;  // edges
static constexpr int Ff    = 128;      // input features
static constexpr int Cc    = 64;       // hidden channels
static constexpr int NHh   = 256;      // nhid
static constexpr int NOUTt = 128;      // nout
static constexpr int Ll    = 4;        // hidden GCN layers
static constexpr int Gg    = 512;      // graphs

static constexpr int SCAN_BLK = 1024;
static constexpr int NBLK_SCAN = (Nn + SCAN_BLK - 1) / SCAN_BLK;   // 98

// partition p = dst & 7 (exactly balanced: 12500 nodes each); permuted node
// index i = p*PART2 + (dst>>3) gives partition-contiguous cnt/cursor/csr.
static constexpr int PART2 = Nn / 8;           // 12500
static constexpr int BCAP  = 220160;           // per-bucket capacity (exp 200k, >14 sigma)

// ---------------- pass 1: bin edges by dst&7 ----------------
// entry = src | ((dst>>3) << 17)   (17 + 14 = 31 bits)
__global__ __launch_bounds__(256) void bin_kernel(const int* __restrict__ src,
                                                  const int* __restrict__ dst,
                                                  int* __restrict__ bucket,
                                                  int* __restrict__ bcur, int E) {
    __shared__ int lcnt[8], lbase[8];
    const int tid = threadIdx.x;
    if (tid < 8) lcnt[tid] = 0;
    __syncthreads();
    const int base = blockIdx.x * 1024;
    int pk[4], pb[4], lr[4];
    #pragma unroll
    for (int i = 0; i < 4; ++i) {
        int e = base + i * 256 + tid;
        if (e < E) {
            int d = dst[e], s = src[e];
            int b = d & 7;
            pb[i] = b;
            pk[i] = s | ((d >> 3) << 17);
            lr[i] = atomicAdd(&lcnt[b], 1);     // LDS rank
        } else pb[i] = -1;
    }
    __syncthreads();
    if (tid < 8) lbase[tid] = atomicAdd(&bcur[tid], lcnt[tid]);
    __syncthreads();
    #pragma unroll
    for (int i = 0; i < 4; ++i) {
        if (pb[i] >= 0) {
            int pos = lbase[pb[i]] + lr[i];
            if (pos < BCAP) bucket[(size_t)pb[i] * BCAP + pos] = pk[i];
        }
    }
}

// ---------------- pass 2a: per-partition degree count (XCD-local) ----------------
__global__ __launch_bounds__(256) void cnt2_kernel(const int* __restrict__ bucket,
                                                   const int* __restrict__ bcur,
                                                   int* __restrict__ cntP) {
    const int p  = blockIdx.x & 7;
    const int c  = blockIdx.x >> 3;
    const int nc = gridDim.x >> 3;
    const int n  = bcur[p];
    const int* bp = bucket + (size_t)p * BCAP;
    int* cp = cntP + p * PART2;
    for (int i = c * 256 + threadIdx.x; i < n; i += nc * 256) {
        int v = bp[i];
        atomicAdd(&cp[v >> 17], 1);
    }
}

// dinv in NATURAL node order, reading permuted cnt
__global__ void dinv_kernel(const int* __restrict__ cntP, float* __restrict__ dinv, int n) {
    int d = blockIdx.x * blockDim.x + threadIdx.x;
    if (d < n) dinv[d] = rsqrtf((float)cntP[(d & 7) * PART2 + (d >> 3)] + 1.0f);
}

// ---------------- scans over permuted cnt (semantics-agnostic) ----------------
__global__ __launch_bounds__(SCAN_BLK) void scan1_kernel(const int* __restrict__ cnt,
                                                         int* __restrict__ row_off,
                                                         int* __restrict__ bsum, int n) {
    __shared__ int sd[SCAN_BLK];
    int tid = threadIdx.x;
    int gid = blockIdx.x * SCAN_BLK + tid;
    int v = (gid < n) ? cnt[gid] : 0;
    sd[tid] = v;
    __syncthreads();
    #pragma unroll
    for (int off = 1; off < SCAN_BLK; off <<= 1) {
        int t = (tid >= off) ? sd[tid - off] : 0;
        __syncthreads();
        sd[tid] += t;
        __syncthreads();
    }
    if (gid < n) row_off[gid + 1] = sd[tid];
    if (tid == SCAN_BLK - 1) bsum[blockIdx.x] = sd[tid];
}

__global__ __launch_bounds__(128) void scan2_kernel(const int* __restrict__ bsum,
                                                    int* __restrict__ boff, int nb) {
    __shared__ int sd[128];
    int tid = threadIdx.x;
    sd[tid] = (tid < nb) ? bsum[tid] : 0;
    __syncthreads();
    #pragma unroll
    for (int off = 1; off < 128; off <<= 1) {
        int t = (tid >= off) ? sd[tid - off] : 0;
        __syncthreads();
        sd[tid] += t;
        __syncthreads();
    }
    if (tid < nb) boff[tid] = (tid == 0) ? 0 : sd[tid - 1];
}

__global__ void scan3_kernel(int* __restrict__ row_off, const int* __restrict__ boff,
                             int* __restrict__ cursor, int n) {
    int gid = blockIdx.x * blockDim.x + threadIdx.x;
    if (gid < n) {
        int v = row_off[gid + 1] + boff[gid >> 10];
        row_off[gid + 1] = v;
        cursor[gid + 1] = v;
    }
    if (gid == 0) { row_off[0] = 0; cursor[0] = 0; }
}

// ---------------- pass 2b: fill csr (XCD-local reads AND writes) ----------------
__global__ __launch_bounds__(256) void fill2_kernel(const int* __restrict__ bucket,
                                                    const int* __restrict__ bcur,
                                                    int* __restrict__ cursorP,
                                                    int* __restrict__ csr_src) {
    const int p  = blockIdx.x & 7;
    const int c  = blockIdx.x >> 3;
    const int nc = gridDim.x >> 3;
    const int n  = bcur[p];
    const int* bp = bucket + (size_t)p * BCAP;
    int* cp = cursorP + p * PART2;
    for (int i = c * 256 + threadIdx.x; i < n; i += nc * 256) {
        int v = bp[i];
        int pos = atomicAdd(&cp[v >> 17], 1);
        csr_src[pos] = v & 0x1FFFF;
    }
}

// ---------------- GEMM: Y[n][64] = dinv[n] * (X[n][CIN] @ W[CIN][64]) ----------------
template<int CIN>
__global__ __launch_bounds__(256) void gemm_xw(const float* __restrict__ X,
                                               const float* __restrict__ W,
                                               const float* __restrict__ dinv,
                                               float* __restrict__ Y, int n) {
    __shared__ float hs[64][68];
    __shared__ float ws[64][64];
    const int tid = threadIdx.x;
    const int tx  = tid & 15;
    const int ty  = tid >> 4;
    const int rowbase = blockIdx.x * 64;

    float acc[4][4] = {};

    for (int k0 = 0; k0 < CIN; k0 += 64) {
        #pragma unroll
        for (int i = 0; i < 4; ++i) {
            int r = ty + i * 16;
            int gr = rowbase + r;
            float4 v = make_float4(0.f, 0.f, 0.f, 0.f);
            if (gr < n) v = *(const float4*)(X + (size_t)gr * CIN + k0 + tx * 4);
            *(float4*)&hs[r][tx * 4] = v;
        }
        #pragma unroll
        for (int i = 0; i < 4; ++i) {
            int k = ty + i * 16;
            *(float4*)&ws[k][tx * 4] = *(const float4*)(W + (size_t)(k0 + k) * 64 + tx * 4);
        }
        __syncthreads();

        #pragma unroll 4
        for (int k = 0; k < 64; ++k) {
            float4 w = *(const float4*)&ws[k][tx * 4];
            float h0 = hs[ty * 4 + 0][k];
            float h1 = hs[ty * 4 + 1][k];
            float h2 = hs[ty * 4 + 2][k];
            float h3 = hs[ty * 4 + 3][k];
            acc[0][0] += h0 * w.x; acc[0][1] += h0 * w.y; acc[0][2] += h0 * w.z; acc[0][3] += h0 * w.w;
            acc[1][0] += h1 * w.x; acc[1][1] += h1 * w.y; acc[1][2] += h1 * w.z; acc[1][3] += h1 * w.w;
            acc[2][0] += h2 * w.x; acc[2][1] += h2 * w.y; acc[2][2] += h2 * w.z; acc[2][3] += h2 * w.w;
            acc[3][0] += h3 * w.x; acc[3][1] += h3 * w.y; acc[3][2] += h3 * w.z; acc[3][3] += h3 * w.w;
        }
        __syncthreads();
    }

    #pragma unroll
    for (int i = 0; i < 4; ++i) {
        int gr = rowbase + ty * 4 + i;
        if (gr < n) {
            float di = dinv[gr];
            float4 v = make_float4(acc[i][0] * di, acc[i][1] * di, acc[i][2] * di, acc[i][3] * di);
            *(float4*)(Y + (size_t)gr * 64 + tx * 4) = v;
        }
    }
}

// ---------------- CSR gather-aggregate (fused finalize; permuted row_off) ----------------
__global__ __launch_bounds__(256) void gather_agg(const int* __restrict__ row_off,
                                                  const int* __restrict__ csr_src,
                                                  const float* __restrict__ dinv,
                                                  const float* __restrict__ t,
                                                  const float* __restrict__ b,
                                                  float* __restrict__ out, int n) {
    const int lane = threadIdx.x & 63;
    const int node = (blockIdx.x * blockDim.x + threadIdx.x) >> 6;
    if (node >= n) return;
    const int sub = lane >> 4;        // 0..3 : edge slot
    const int c4  = lane & 15;        // float4 slot within row

    const int pi   = (node & 7) * PART2 + (node >> 3);   // permuted index
    const int base = row_off[pi];
    const int end  = row_off[pi + 1];

    float4 acc = make_float4(0.f, 0.f, 0.f, 0.f);

    for (int k0 = base; k0 < end; k0 += 64) {
        int myidx = (k0 + lane < end) ? csr_src[k0 + lane] : 0;
        int nk = min(64, end - k0);
        int k = 0;
        for (; k + 8 <= nk; k += 8) {
            int s0 = __shfl(myidx, k + sub);
            int s1 = __shfl(myidx, k + 4 + sub);
            float4 v0 = *(const float4*)(t + (size_t)s0 * 64 + c4 * 4);
            float4 v1 = *(const float4*)(t + (size_t)s1 * 64 + c4 * 4);
            acc.x += v0.x; acc.y += v0.y; acc.z += v0.z; acc.w += v0.w;
            acc.x += v1.x; acc.y += v1.y; acc.z += v1.z; acc.w += v1.w;
        }
        for (; k < nk; k += 4) {
            int kk = k + sub;
            int s = __shfl(myidx, kk);
            if (kk < nk) {
                float4 v = *(const float4*)(t + (size_t)s * 64 + c4 * 4);
                acc.x += v.x; acc.y += v.y; acc.z += v.z; acc.w += v.w;
            }
        }
    }

    #pragma unroll
    for (int off = 16; off < 64; off <<= 1) {
        acc.x += __shfl_xor(acc.x, off);
        acc.y += __shfl_xor(acc.y, off);
        acc.z += __shfl_xor(acc.z, off);
        acc.w += __shfl_xor(acc.w, off);
    }

    if (sub == 0) {
        float di = dinv[node];
        float4 self = *(const float4*)(t + (size_t)node * 64 + c4 * 4);
        float4 bb   = *(const float4*)(b + c4 * 4);
        float4 r;
        r.x = fmaxf(di * (acc.x + self.x) + bb.x, 0.f);
        r.y = fmaxf(di * (acc.y + self.y) + bb.y, 0.f);
        r.z = fmaxf(di * (acc.z + self.z) + bb.z, 0.f);
        r.w = fmaxf(di * (acc.w + self.w) + bb.w, 0.f);
        *(float4*)(out + (size_t)node * 64 + c4 * 4) = r;
    }
}

// ---------------- pooling via sorted-batch segments ----------------
__global__ void gbounds_kernel(const int* __restrict__ batch, int* __restrict__ gstart, int n) {
    int i = blockIdx.x * blockDim.x + threadIdx.x;
    if (i >= n) return;
    int bi = batch[i];
    int bp = (i == 0) ? -1 : batch[i - 1];
    for (int g = bp + 1; g <= bi; ++g) gstart[g] = i;
    if (i == n - 1) {
        for (int g = bi + 1; g <= Gg; ++g) gstart[g] = n;
    }
}

__global__ __launch_bounds__(256) void pool_graph(const float* __restrict__ h,
                                                  const int* __restrict__ gstart,
                                                  float* __restrict__ pooled) {
    __shared__ float sd[4][64];
    const int g    = blockIdx.x;
    const int lane = threadIdx.x & 63;
    const int wv   = threadIdx.x >> 6;
    const int s = gstart[g], e = gstart[g + 1];
    float acc = 0.f;
    for (int i = s + wv; i < e; i += 4) acc += h[(size_t)i * 64 + lane];
    sd[wv][lane] = acc;
    __syncthreads();
    if (wv == 0) {
        float sum = sd[0][lane] + sd[1][lane] + sd[2][lane] + sd[3][lane];
        float c = (float)(e - s);
        pooled[(size_t)g * 64 + lane] = sum / fmaxf(c, 1.f);
    }
}

// ---------------- MLP head ----------------
__global__ void mlp1_kernel(const float* __restrict__ P, const float* __restrict__ W1,
                            const float* __restrict__ b1, float* __restrict__ H) {
    int gid = blockIdx.x * blockDim.x + threadIdx.x;
    if (gid >= Gg * NHh) return;
    int j = gid & (NHh - 1), g = gid >> 8;
    const float* p = P + (size_t)g * Cc;
    float s = b1[j];
    #pragma unroll 8
    for (int k = 0; k < Cc; ++k) s += p[k] * W1[(size_t)k * NHh + j];
    H[gid] = fmaxf(s, 0.f);
}

__global__ void mlp2_kernel(const float* __restrict__ H, const float* __restrict__ W2,
                            const float* __restrict__ b2, float* __restrict__ O) {
    int gid = blockIdx.x * blockDim.x + threadIdx.x;
    if (gid >= Gg * NOUTt) return;
    int j = gid & (NOUTt - 1), g = gid >> 7;
    const float* h = H + (size_t)g * NHh;
    float s = b2[j];
    #pragma unroll 8
    for (int k = 0; k < NHh; ++k) s += h[k] * W2[(size_t)k * NOUTt + j];
    O[gid] = s;
}

// ---------------- launch ----------------
extern "C" void kernel_launch(void* const* d_in, const int* in_sizes, int n_in,
                              void* d_out, int out_size, void* d_ws, size_t ws_size,
                              hipStream_t stream) {
    const float* x     = (const float*)d_in[0];
    const int*   ei    = (const int*)  d_in[1];
    const int*   batch = (const int*)  d_in[2];
    const float* W0    = (const float*)d_in[3];
    const float* b0    = (const float*)d_in[4];
    const float* Wh    = (const float*)d_in[5];
    const float* bh    = (const float*)d_in[6];
    const float* W1    = (const float*)d_in[7];
    const float* b1    = (const float*)d_in[8];
    const float* W2    = (const float*)d_in[9];
    const float* b2    = (const float*)d_in[10];

    const int* src = ei;
    const int* dst = ei + Ee;

    char* ws = (char*)d_ws;
    constexpr size_t OFF_DINV  = 0;
    constexpr size_t OFF_CNT   = 400384;
    constexpr size_t OFF_ROFF  = OFF_CNT + 400384;
    constexpr size_t OFF_BSUM  = OFF_ROFF + 400384;
    constexpr size_t OFF_BOFF  = OFF_BSUM + 1024;
    constexpr size_t OFF_CUR   = OFF_BOFF + 1024;
    constexpr size_t OFF_BCNT  = OFF_CUR + 400384;
    constexpr size_t OFF_CSR   = OFF_BCNT + 1024;
    constexpr size_t OFF_B     = OFF_CSR + (size_t)Ee * 4;
    constexpr size_t OFF_A     = OFF_B + (size_t)Nn * 64 * 4;
    constexpr size_t OFF_POOL  = OFF_A + (size_t)Nn * 64 * 4;
    constexpr size_t OFF_GST   = OFF_POOL + (size_t)Gg * Cc * 4;
    constexpr size_t OFF_HID   = OFF_GST + 4096;
    // buckets alias B (dead until first gemm): 8 * BCAP * 4 = 7.04MB <= 25.6MB
    const size_t OFF_BKT = OFF_B;

    float* dinv   = (float*)(ws + OFF_DINV);
    int*   cnt    = (int*)  (ws + OFF_CNT);     // permuted-space degree
    int*   roff   = (int*)  (ws + OFF_ROFF);    // permuted-space row offsets
    int*   bsum   = (int*)  (ws + OFF_BSUM);
    int*   boff   = (int*)  (ws + OFF_BOFF);
    int*   cursor = (int*)  (ws + OFF_CUR);
    int*   bcnt   = (int*)  (ws + OFF_BCNT);
    int*   csrs   = (int*)  (ws + OFF_CSR);
    int*   bkt    = (int*)  (ws + OFF_BKT);
    float* B      = (float*)(ws + OFF_B);
    float* A      = (float*)(ws + OFF_A);
    float* pooled = (float*)(ws + OFF_POOL);
    int*   gstart = (int*)  (ws + OFF_GST);
    float* hid    = (float*)(ws + OFF_HID);

    // ---- CSR build: bin -> cnt2 -> scans -> fill2 ----
    hipMemsetAsync(cnt, 0, (size_t)Nn * 4, stream);
    hipMemsetAsync(bcnt, 0, 1024, stream);
    bin_kernel<<<(Ee + 1023) / 1024, 256, 0, stream>>>(src, dst, bkt, bcnt, Ee);
    cnt2_kernel<<<2048, 256, 0, stream>>>(bkt, bcnt, cnt);
    dinv_kernel<<<(Nn + 255) / 256, 256, 0, stream>>>(cnt, dinv, Nn);
    scan1_kernel<<<NBLK_SCAN, SCAN_BLK, 0, stream>>>(cnt, roff, bsum, Nn);
    scan2_kernel<<<1, 128, 0, stream>>>(bsum, boff, NBLK_SCAN);
    scan3_kernel<<<(Nn + 255) / 256, 256, 0, stream>>>(roff, boff, cursor, Nn);
    fill2_kernel<<<2048, 256, 0, stream>>>(bkt, bcnt, cursor, csrs);

    // ---- graph boundaries from sorted batch ----
    gbounds_kernel<<<(Nn + 255) / 256, 256, 0, stream>>>(batch, gstart, Nn);

    const int gemm_blocks = (Nn + 63) / 64;
    const int agg_blocks  = (Nn * 64 + 255) / 256;

    // ---- layer 0 ----
    gemm_xw<128><<<gemm_blocks, 256, 0, stream>>>(x, W0, dinv, B, Nn);
    gather_agg<<<agg_blocks, 256, 0, stream>>>(roff, csrs, dinv, B, b0, A, Nn);

    // ---- hidden layers ----
    for (int i = 0; i < Ll; ++i) {
        gemm_xw<64><<<gemm_blocks, 256, 0, stream>>>(A, Wh + (size_t)i * Cc * Cc, dinv, B, Nn);
        gather_agg<<<agg_blocks, 256, 0, stream>>>(roff, csrs, dinv, B, bh + (size_t)i * Cc, A, Nn);
    }

    // ---- global mean pool (segmented, no atomics) ----
    pool_graph<<<Gg, 256, 0, stream>>>(A, gstart, pooled);

    // ---- MLP head ----
    mlp1_kernel<<<(Gg * NHh + 255) / 256, 256, 0, stream>>>(pooled, W1, b1, hid);
    mlp2_kernel<<<(Gg * NOUTt + 255) / 256, 256, 0, stream>>>(hid, W2, b2, (float*)d_out);
}

// Round 8
// 494.581 us; speedup vs baseline: 1.2392x; 1.2392x over previous
//
#include <hip/hip_runtime.h>
#include <stddef.h>

static constexpr int Nn    = 100000;   // nodes
static constexpr int Ee    = 1600000;  // edges
static constexpr int Ff    = 128;      // input features
static constexpr int Cc    = 64;       // hidden channels
static constexpr int NHh   = 256;      // nhid
static constexpr int NOUTt = 128;      // nout
static constexpr int Ll    = 4;        // hidden GCN layers
static constexpr int Gg    = 512;      // graphs

static constexpr int SCAN_BLK = 1024;
static constexpr int NBLK_SCAN = (Nn + SCAN_BLK - 1) / SCAN_BLK;   // 98

// sub-bucket = 512 contiguous nodes (dst>>9); one block owns one sub-bucket's
// csr segment -> all its dirty lines live in ONE L2 and flush once.
static constexpr int NSUB   = (Nn + 511) / 512;   // 196
static constexpr int SUBCAP = 10240;              // mean 8192, sigma~90 -> +22 sigma

// ---------------- pass 1: bin edges by dst>>9 into 196 sub-buckets ----------------
// entry = src | ((dst & 511) << 17)   (17 + 9 = 26 bits)
__global__ __launch_bounds__(256) void bin_kernel(const int* __restrict__ src,
                                                  const int* __restrict__ dst,
                                                  int* __restrict__ sb,
                                                  int* __restrict__ scnt, int E) {
    __shared__ int lcnt[NSUB], lbase[NSUB];
    const int tid = threadIdx.x;
    for (int i = tid; i < NSUB; i += 256) lcnt[i] = 0;
    __syncthreads();
    const int base = blockIdx.x * 2048;
    int pk[8], ps[8], lr[8];
    #pragma unroll
    for (int i = 0; i < 8; ++i) {
        int e = base + i * 256 + tid;
        if (e < E) {
            int d = dst[e], s = src[e];
            int sub = d >> 9;
            ps[i] = sub;
            pk[i] = s | ((d & 511) << 17);
            lr[i] = atomicAdd(&lcnt[sub], 1);    // LDS rank
        } else ps[i] = -1;
    }
    __syncthreads();
    for (int i = tid; i < NSUB; i += 256) lbase[i] = atomicAdd(&scnt[i], lcnt[i]);
    __syncthreads();
    #pragma unroll
    for (int i = 0; i < 8; ++i) {
        if (ps[i] >= 0) {
            int pos = lbase[ps[i]] + lr[i];
            if (pos < SUBCAP) sb[(size_t)ps[i] * SUBCAP + pos] = pk[i];
        }
    }
}

// ---------------- pass 2a: per-node degree (one block per sub-bucket) ----------------
__global__ __launch_bounds__(512) void cnt3_kernel(const int* __restrict__ sb,
                                                   const int* __restrict__ scnt,
                                                   int* __restrict__ cnt) {
    __shared__ int lcnt[512];
    const int sub = blockIdx.x, tid = threadIdx.x;
    lcnt[tid] = 0;
    __syncthreads();
    const int n = scnt[sub];
    const int* bp = sb + (size_t)sub * SUBCAP;
    for (int i = tid; i < n; i += 512) atomicAdd(&lcnt[(bp[i] >> 17) & 511], 1);
    __syncthreads();
    int node = sub * 512 + tid;
    if (node < Nn) cnt[node] = lcnt[tid];
}

__global__ void dinv_kernel(const int* __restrict__ cnt, float* __restrict__ dinv, int n) {
    int i = blockIdx.x * blockDim.x + threadIdx.x;
    if (i < n) dinv[i] = rsqrtf((float)cnt[i] + 1.0f);   // + self loop
}

// ---------------- scans ----------------
__global__ __launch_bounds__(SCAN_BLK) void scan1_kernel(const int* __restrict__ cnt,
                                                         int* __restrict__ row_off,
                                                         int* __restrict__ bsum, int n) {
    __shared__ int sd[SCAN_BLK];
    int tid = threadIdx.x;
    int gid = blockIdx.x * SCAN_BLK + tid;
    int v = (gid < n) ? cnt[gid] : 0;
    sd[tid] = v;
    __syncthreads();
    #pragma unroll
    for (int off = 1; off < SCAN_BLK; off <<= 1) {
        int t = (tid >= off) ? sd[tid - off] : 0;
        __syncthreads();
        sd[tid] += t;
        __syncthreads();
    }
    if (gid < n) row_off[gid + 1] = sd[tid];
    if (tid == SCAN_BLK - 1) bsum[blockIdx.x] = sd[tid];
}

__global__ __launch_bounds__(128) void scan2_kernel(const int* __restrict__ bsum,
                                                    int* __restrict__ boff, int nb) {
    __shared__ int sd[128];
    int tid = threadIdx.x;
    sd[tid] = (tid < nb) ? bsum[tid] : 0;
    __syncthreads();
    #pragma unroll
    for (int off = 1; off < 128; off <<= 1) {
        int t = (tid >= off) ? sd[tid - off] : 0;
        __syncthreads();
        sd[tid] += t;
        __syncthreads();
    }
    if (tid < nb) boff[tid] = (tid == 0) ? 0 : sd[tid - 1];
}

__global__ void scan3_kernel(int* __restrict__ row_off, const int* __restrict__ boff, int n) {
    int gid = blockIdx.x * blockDim.x + threadIdx.x;
    if (gid < n) row_off[gid + 1] += boff[gid >> 10];
    if (gid == 0) row_off[0] = 0;
}

// ---------------- pass 2b: fill csr (one block per sub-bucket, block-owned writes) ----------------
__global__ __launch_bounds__(512) void fill3_kernel(const int* __restrict__ sb,
                                                    const int* __restrict__ scnt,
                                                    const int* __restrict__ roff,
                                                    int* __restrict__ csr) {
    __shared__ int lcnt[512], lofs[512];
    __shared__ int gbase;
    const int sub = blockIdx.x, tid = threadIdx.x;
    lcnt[tid] = 0;
    if (tid == 0) gbase = roff[sub * 512];
    __syncthreads();
    const int n = scnt[sub];
    const int* bp = sb + (size_t)sub * SUBCAP;
    for (int i = tid; i < n; i += 512) atomicAdd(&lcnt[(bp[i] >> 17) & 511], 1);
    __syncthreads();
    // inclusive scan of lcnt -> lofs
    int v = lcnt[tid];
    lofs[tid] = v;
    __syncthreads();
    #pragma unroll
    for (int off = 1; off < 512; off <<= 1) {
        int t = (tid >= off) ? lofs[tid - off] : 0;
        __syncthreads();
        lofs[tid] += t;
        __syncthreads();
    }
    int excl = lofs[tid] - v;      // exclusive start for my node
    __syncthreads();
    lcnt[tid] = excl;              // reuse as running cursor
    __syncthreads();
    for (int i = tid; i < n; i += 512) {
        int e = bp[i];
        int pos = atomicAdd(&lcnt[(e >> 17) & 511], 1);
        csr[gbase + pos] = e & 0x1FFFF;
    }
}

// ---------------- GEMM: Y[n][64] = dinv[n] * (X[n][CIN] @ W[CIN][64]) ----------------
template<int CIN>
__global__ __launch_bounds__(256) void gemm_xw(const float* __restrict__ X,
                                               const float* __restrict__ W,
                                               const float* __restrict__ dinv,
                                               float* __restrict__ Y, int n) {
    __shared__ float hs[64][68];
    __shared__ float ws[64][64];
    const int tid = threadIdx.x;
    const int tx  = tid & 15;
    const int ty  = tid >> 4;
    const int rowbase = blockIdx.x * 64;

    float acc[4][4] = {};

    for (int k0 = 0; k0 < CIN; k0 += 64) {
        #pragma unroll
        for (int i = 0; i < 4; ++i) {
            int r = ty + i * 16;
            int gr = rowbase + r;
            float4 v = make_float4(0.f, 0.f, 0.f, 0.f);
            if (gr < n) v = *(const float4*)(X + (size_t)gr * CIN + k0 + tx * 4);
            *(float4*)&hs[r][tx * 4] = v;
        }
        #pragma unroll
        for (int i = 0; i < 4; ++i) {
            int k = ty + i * 16;
            *(float4*)&ws[k][tx * 4] = *(const float4*)(W + (size_t)(k0 + k) * 64 + tx * 4);
        }
        __syncthreads();

        #pragma unroll 4
        for (int k = 0; k < 64; ++k) {
            float4 w = *(const float4*)&ws[k][tx * 4];
            float h0 = hs[ty * 4 + 0][k];
            float h1 = hs[ty * 4 + 1][k];
            float h2 = hs[ty * 4 + 2][k];
            float h3 = hs[ty * 4 + 3][k];
            acc[0][0] += h0 * w.x; acc[0][1] += h0 * w.y; acc[0][2] += h0 * w.z; acc[0][3] += h0 * w.w;
            acc[1][0] += h1 * w.x; acc[1][1] += h1 * w.y; acc[1][2] += h1 * w.z; acc[1][3] += h1 * w.w;
            acc[2][0] += h2 * w.x; acc[2][1] += h2 * w.y; acc[2][2] += h2 * w.z; acc[2][3] += h2 * w.w;
            acc[3][0] += h3 * w.x; acc[3][1] += h3 * w.y; acc[3][2] += h3 * w.z; acc[3][3] += h3 * w.w;
        }
        __syncthreads();
    }

    #pragma unroll
    for (int i = 0; i < 4; ++i) {
        int gr = rowbase + ty * 4 + i;
        if (gr < n) {
            float di = dinv[gr];
            float4 v = make_float4(acc[i][0] * di, acc[i][1] * di, acc[i][2] * di, acc[i][3] * di);
            *(float4*)(Y + (size_t)gr * 64 + tx * 4) = v;
        }
    }
}

// ---------------- CSR gather-aggregate (fused finalize) ----------------
__global__ __launch_bounds__(256) void gather_agg(const int* __restrict__ row_off,
                                                  const int* __restrict__ csr_src,
                                                  const float* __restrict__ dinv,
                                                  const float* __restrict__ t,
                                                  const float* __restrict__ b,
                                                  float* __restrict__ out, int n) {
    const int lane = threadIdx.x & 63;
    const int node = (blockIdx.x * blockDim.x + threadIdx.x) >> 6;
    if (node >= n) return;
    const int sub = lane >> 4;        // 0..3 : edge slot
    const int c4  = lane & 15;        // float4 slot within row

    const int base = row_off[node];
    const int end  = row_off[node + 1];

    float4 acc = make_float4(0.f, 0.f, 0.f, 0.f);

    for (int k0 = base; k0 < end; k0 += 64) {
        int myidx = (k0 + lane < end) ? csr_src[k0 + lane] : 0;
        int nk = min(64, end - k0);
        int k = 0;
        for (; k + 8 <= nk; k += 8) {
            int s0 = __shfl(myidx, k + sub);
            int s1 = __shfl(myidx, k + 4 + sub);
            float4 v0 = *(const float4*)(t + (size_t)s0 * 64 + c4 * 4);
            float4 v1 = *(const float4*)(t + (size_t)s1 * 64 + c4 * 4);
            acc.x += v0.x; acc.y += v0.y; acc.z += v0.z; acc.w += v0.w;
            acc.x += v1.x; acc.y += v1.y; acc.z += v1.z; acc.w += v1.w;
        }
        for (; k < nk; k += 4) {
            int kk = k + sub;
            int s = __shfl(myidx, kk);
            if (kk < nk) {
                float4 v = *(const float4*)(t + (size_t)s * 64 + c4 * 4);
                acc.x += v.x; acc.y += v.y; acc.z += v.z; acc.w += v.w;
            }
        }
    }

    #pragma unroll
    for (int off = 16; off < 64; off <<= 1) {
        acc.x += __shfl_xor(acc.x, off);
        acc.y += __shfl_xor(acc.y, off);
        acc.z += __shfl_xor(acc.z, off);
        acc.w += __shfl_xor(acc.w, off);
    }

    if (sub == 0) {
        float di = dinv[node];
        float4 self = *(const float4*)(t + (size_t)node * 64 + c4 * 4);
        float4 bb   = *(const float4*)(b + c4 * 4);
        float4 r;
        r.x = fmaxf(di * (acc.x + self.x) + bb.x, 0.f);
        r.y = fmaxf(di * (acc.y + self.y) + bb.y, 0.f);
        r.z = fmaxf(di * (acc.z + self.z) + bb.z, 0.f);
        r.w = fmaxf(di * (acc.w + self.w) + bb.w, 0.f);
        *(float4*)(out + (size_t)node * 64 + c4 * 4) = r;
    }
}

// ---------------- pooling via sorted-batch segments ----------------
__global__ void gbounds_kernel(const int* __restrict__ batch, int* __restrict__ gstart, int n) {
    int i = blockIdx.x * blockDim.x + threadIdx.x;
    if (i >= n) return;
    int bi = batch[i];
    int bp = (i == 0) ? -1 : batch[i - 1];
    for (int g = bp + 1; g <= bi; ++g) gstart[g] = i;
    if (i == n - 1) {
        for (int g = bi + 1; g <= Gg; ++g) gstart[g] = n;
    }
}

__global__ __launch_bounds__(256) void pool_graph(const float* __restrict__ h,
                                                  const int* __restrict__ gstart,
                                                  float* __restrict__ pooled) {
    __shared__ float sd[4][64];
    const int g    = blockIdx.x;
    const int lane = threadIdx.x & 63;
    const int wv   = threadIdx.x >> 6;
    const int s = gstart[g], e = gstart[g + 1];
    float acc = 0.f;
    for (int i = s + wv; i < e; i += 4) acc += h[(size_t)i * 64 + lane];
    sd[wv][lane] = acc;
    __syncthreads();
    if (wv == 0) {
        float sum = sd[0][lane] + sd[1][lane] + sd[2][lane] + sd[3][lane];
        float c = (float)(e - s);
        pooled[(size_t)g * 64 + lane] = sum / fmaxf(c, 1.f);
    }
}

// ---------------- MLP head ----------------
__global__ void mlp1_kernel(const float* __restrict__ P, const float* __restrict__ W1,
                            const float* __restrict__ b1, float* __restrict__ H) {
    int gid = blockIdx.x * blockDim.x + threadIdx.x;
    if (gid >= Gg * NHh) return;
    int j = gid & (NHh - 1), g = gid >> 8;
    const float* p = P + (size_t)g * Cc;
    float s = b1[j];
    #pragma unroll 8
    for (int k = 0; k < Cc; ++k) s += p[k] * W1[(size_t)k * NHh + j];
    H[gid] = fmaxf(s, 0.f);
}

__global__ void mlp2_kernel(const float* __restrict__ H, const float* __restrict__ W2,
                            const float* __restrict__ b2, float* __restrict__ O) {
    int gid = blockIdx.x * blockDim.x + threadIdx.x;
    if (gid >= Gg * NOUTt) return;
    int j = gid & (NOUTt - 1), g = gid >> 7;
    const float* h = H + (size_t)g * NHh;
    float s = b2[j];
    #pragma unroll 8
    for (int k = 0; k < NHh; ++k) s += h[k] * W2[(size_t)k * NOUTt + j];
    O[gid] = s;
}

// ---------------- launch ----------------
extern "C" void kernel_launch(void* const* d_in, const int* in_sizes, int n_in,
                              void* d_out, int out_size, void* d_ws, size_t ws_size,
                              hipStream_t stream) {
    const float* x     = (const float*)d_in[0];
    const int*   ei    = (const int*)  d_in[1];
    const int*   batch = (const int*)  d_in[2];
    const float* W0    = (const float*)d_in[3];
    const float* b0    = (const float*)d_in[4];
    const float* Wh    = (const float*)d_in[5];
    const float* bh    = (const float*)d_in[6];
    const float* W1    = (const float*)d_in[7];
    const float* b1    = (const float*)d_in[8];
    const float* W2    = (const float*)d_in[9];
    const float* b2    = (const float*)d_in[10];

    const int* src = ei;
    const int* dst = ei + Ee;

    char* ws = (char*)d_ws;
    constexpr size_t OFF_DINV  = 0;
    constexpr size_t OFF_CNT   = 400384;
    constexpr size_t OFF_ROFF  = OFF_CNT + 400384;
    constexpr size_t OFF_BSUM  = OFF_ROFF + 400384;
    constexpr size_t OFF_BOFF  = OFF_BSUM + 1024;
    constexpr size_t OFF_SCNT  = OFF_BOFF + 1024;                  // 196*4 -> 1024
    constexpr size_t OFF_CSR   = OFF_SCNT + 1024;
    constexpr size_t OFF_B     = OFF_CSR + (size_t)Ee * 4;
    constexpr size_t OFF_A     = OFF_B + (size_t)Nn * 64 * 4;
    constexpr size_t OFF_POOL  = OFF_A + (size_t)Nn * 64 * 4;
    constexpr size_t OFF_GST   = OFF_POOL + (size_t)Gg * Cc * 4;
    constexpr size_t OFF_HID   = OFF_GST + 4096;
    // sub-buckets alias B (dead until first gemm): 196 * 10240 * 4 = 8.03MB <= 25.6MB
    const size_t OFF_SB = OFF_B;

    float* dinv   = (float*)(ws + OFF_DINV);
    int*   cnt    = (int*)  (ws + OFF_CNT);
    int*   roff   = (int*)  (ws + OFF_ROFF);
    int*   bsum   = (int*)  (ws + OFF_BSUM);
    int*   boff   = (int*)  (ws + OFF_BOFF);
    int*   scnt   = (int*)  (ws + OFF_SCNT);
    int*   csrs   = (int*)  (ws + OFF_CSR);
    int*   sb     = (int*)  (ws + OFF_SB);
    float* B      = (float*)(ws + OFF_B);
    float* A      = (float*)(ws + OFF_A);
    float* pooled = (float*)(ws + OFF_POOL);
    int*   gstart = (int*)  (ws + OFF_GST);
    float* hid    = (float*)(ws + OFF_HID);

    // ---- CSR build: bin -> cnt3 -> scans -> fill3 ----
    hipMemsetAsync(scnt, 0, 1024, stream);
    bin_kernel<<<(Ee + 2047) / 2048, 256, 0, stream>>>(src, dst, sb, scnt, Ee);
    cnt3_kernel<<<NSUB, 512, 0, stream>>>(sb, scnt, cnt);
    dinv_kernel<<<(Nn + 255) / 256, 256, 0, stream>>>(cnt, dinv, Nn);
    scan1_kernel<<<NBLK_SCAN, SCAN_BLK, 0, stream>>>(cnt, roff, bsum, Nn);
    scan2_kernel<<<1, 128, 0, stream>>>(bsum, boff, NBLK_SCAN);
    scan3_kernel<<<(Nn + 255) / 256, 256, 0, stream>>>(roff, boff, Nn);
    fill3_kernel<<<NSUB, 512, 0, stream>>>(sb, scnt, roff, csrs);

    // ---- graph boundaries from sorted batch ----
    gbounds_kernel<<<(Nn + 255) / 256, 256, 0, stream>>>(batch, gstart, Nn);

    const int gemm_blocks = (Nn + 63) / 64;
    const int agg_blocks  = (Nn * 64 + 255) / 256;

    // ---- layer 0 ----
    gemm_xw<128><<<gemm_blocks, 256, 0, stream>>>(x, W0, dinv, B, Nn);
    gather_agg<<<agg_blocks, 256, 0, stream>>>(roff, csrs, dinv, B, b0, A, Nn);

    // ---- hidden layers ----
    for (int i = 0; i < Ll; ++i) {
        gemm_xw<64><<<gemm_blocks, 256, 0, stream>>>(A, Wh + (size_t)i * Cc * Cc, dinv, B, Nn);
        gather_agg<<<agg_blocks, 256, 0, stream>>>(roff, csrs, dinv, B, bh + (size_t)i * Cc, A, Nn);
    }

    // ---- global mean pool (segmented, no atomics) ----
    pool_graph<<<Gg, 256, 0, stream>>>(A, gstart, pooled);

    // ---- MLP head ----
    mlp1_kernel<<<(Gg * NHh + 255) / 256, 256, 0, stream>>>(pooled, W1, b1, hid);
    mlp2_kernel<<<(Gg * NOUTt + 255) / 256, 256, 0, stream>>>(hid, W2, b2, (float*)d_out);
}